// Round 1
// baseline (1470.551 us; speedup 1.0000x reference)
//
#include <hip/hip_runtime.h>
#include <hip/hip_bf16.h>

// Problem constants
#define BB 4
#define SS 2048
#define HIDD 1024
#define NH 16
#define HD 64
#define BH (BB * NH)   // 64

typedef __attribute__((ext_vector_type(8))) short short8;
typedef __attribute__((ext_vector_type(4))) float floatx4;

__device__ __forceinline__ short f2bf(float f) {
  unsigned u = __float_as_uint(f);
  unsigned r = (u + 0x7FFFu + ((u >> 16) & 1u)) >> 16;  // RNE
  return (short)r;
}

// ---------------------------------------------------------------------------
// Projection GEMM:  P = X @ W^T + bias   (M=8192, N=1024, K=1024), 3x via z.
// Output bf16:
//   z=0 -> qh [B,H,S,D], z=1 -> kh [B,H,S,D], z=2 -> vt [B,H,D,S] (transposed)
// 128x128 tile, BK=64, 4 waves (each 64x64), 16x16x32 bf16 MFMA.
// LDS tiles stored K-contiguous with XOR-16B-segment swizzle (seg ^= row&7).
// ---------------------------------------------------------------------------
__global__ __launch_bounds__(256) void proj_kernel(
    const float* __restrict__ xq, const float* __restrict__ xk,
    const float* __restrict__ xv,
    const float* __restrict__ wq, const float* __restrict__ bq,
    const float* __restrict__ wk, const float* __restrict__ bk,
    const float* __restrict__ wv, const float* __restrict__ bv,
    short* __restrict__ qh, short* __restrict__ kh, short* __restrict__ vt)
{
  const int z = blockIdx.z;
  const float* __restrict__ X    = (z == 0) ? xq : (z == 1) ? xk : xv;
  const float* __restrict__ W    = (z == 0) ? wq : (z == 1) ? wk : wv;
  const float* __restrict__ bias = (z == 0) ? bq : (z == 1) ? bk : bv;

  const int m0 = blockIdx.x * 128;   // over B*S = 8192
  const int n0 = blockIdx.y * 128;   // over HID = 1024

  __shared__ __align__(16) short Asm_[128 * 64];
  __shared__ __align__(16) short Bsm_[128 * 64];

  const int tid  = threadIdx.x;
  const int w    = tid >> 6;
  const int lane = tid & 63;
  const int quad = lane >> 4;
  const int c    = lane & 15;
  const int wm   = w & 1;
  const int wn   = w >> 1;

  floatx4 acc[4][4];
#pragma unroll
  for (int i = 0; i < 4; i++)
#pragma unroll
    for (int j = 0; j < 4; j++) acc[i][j] = (floatx4){0.f, 0.f, 0.f, 0.f};

  for (int k0 = 0; k0 < 1024; k0 += 64) {
    // stage A and B tiles (fp32 -> bf16), swizzled: slot(row,seg) holds
    // global seg (seg ^ (row&7)); 1024 slots of 16B per tile, 4 per thread.
#pragma unroll
    for (int i = 0; i < 4; i++) {
      int slot = tid + i * 256;
      int row  = slot >> 3;
      int seg  = slot & 7;
      int gs   = seg ^ (row & 7);
      const float* sa = X + (size_t)(m0 + row) * 1024 + k0 + gs * 8;
      floatx4 a0 = *(const floatx4*)sa;
      floatx4 a1 = *(const floatx4*)(sa + 4);
      short8 pa;
      pa[0] = f2bf(a0[0]); pa[1] = f2bf(a0[1]); pa[2] = f2bf(a0[2]); pa[3] = f2bf(a0[3]);
      pa[4] = f2bf(a1[0]); pa[5] = f2bf(a1[1]); pa[6] = f2bf(a1[2]); pa[7] = f2bf(a1[3]);
      *(short8*)&Asm_[row * 64 + seg * 8] = pa;

      const float* sb = W + (size_t)(n0 + row) * 1024 + k0 + gs * 8;
      floatx4 b0 = *(const floatx4*)sb;
      floatx4 b1 = *(const floatx4*)(sb + 4);
      short8 pb;
      pb[0] = f2bf(b0[0]); pb[1] = f2bf(b0[1]); pb[2] = f2bf(b0[2]); pb[3] = f2bf(b0[3]);
      pb[4] = f2bf(b1[0]); pb[5] = f2bf(b1[1]); pb[6] = f2bf(b1[2]); pb[7] = f2bf(b1[3]);
      *(short8*)&Bsm_[row * 64 + seg * 8] = pb;
    }
    __syncthreads();

#pragma unroll
    for (int ks = 0; ks < 2; ks++) {
      short8 af[4], bf8[4];
#pragma unroll
      for (int i = 0; i < 4; i++) {
        int ar = wm * 64 + i * 16 + c;
        af[i]  = *(short8*)&Asm_[ar * 64 + ((ks * 4 + quad) ^ (ar & 7)) * 8];
        int br = wn * 64 + i * 16 + c;
        bf8[i] = *(short8*)&Bsm_[br * 64 + ((ks * 4 + quad) ^ (br & 7)) * 8];
      }
#pragma unroll
      for (int mi = 0; mi < 4; mi++)
#pragma unroll
        for (int ni = 0; ni < 4; ni++)
          acc[mi][ni] = __builtin_amdgcn_mfma_f32_16x16x32_bf16(
              af[mi], bf8[ni], acc[mi][ni], 0, 0, 0);
    }
    __syncthreads();
  }

  // epilogue: bias + bf16 + scatter to head layout
  float bval[4];
#pragma unroll
  for (int ni = 0; ni < 4; ni++) bval[ni] = bias[n0 + wn * 64 + ni * 16 + c];

  if (z < 2) {
    short* dst = (z == 0) ? qh : kh;
#pragma unroll
    for (int mi = 0; mi < 4; mi++) {
#pragma unroll
      for (int ni = 0; ni < 4; ni++) {
        int n  = n0 + wn * 64 + ni * 16 + c;
        int hh = n >> 6, dd = n & 63;
#pragma unroll
        for (int r = 0; r < 4; r++) {
          int m  = m0 + wm * 64 + mi * 16 + quad * 4 + r;
          int bb = m >> 11, s = m & 2047;
          float val = acc[mi][ni][r] + bval[ni];
          dst[(((size_t)(bb * NH + hh)) * SS + s) * HD + dd] = f2bf(val);
        }
      }
    }
  } else {
#pragma unroll
    for (int mi = 0; mi < 4; mi++) {
#pragma unroll
      for (int ni = 0; ni < 4; ni++) {
        int n  = n0 + wn * 64 + ni * 16 + c;
        int hh = n >> 6, dd = n & 63;
#pragma unroll
        for (int r = 0; r < 4; r++) {
          int m  = m0 + wm * 64 + mi * 16 + quad * 4 + r;
          int bb = m >> 11, s = m & 2047;
          float val = acc[mi][ni][r] + bval[ni];
          vt[(((size_t)(bb * NH + hh)) * HD + dd) * SS + s] = f2bf(val);
        }
      }
    }
  }
}

// ---------------------------------------------------------------------------
// Attention: per block = one (b,h) x 64 q-rows. 4 waves, each owns 16 q-rows.
// Two passes over keys in 128-chunks:
//   pass 1: S = QK^T/8 + mask -> accumulate row exp-sums l (no max; clamp 30)
//   pass 2: recompute S, p = exp(s)/l, write p (fp32) to scores out,
//           P->bf16 via padded LDS (C-layout -> A-layout), O += P·V (MFMA).
// K staged [key][d] swizzled; V staged from pre-transposed vt as [d][key]
// swizzled; P buffer padded to 136 shorts/row (bank-conflict free).
// ---------------------------------------------------------------------------
__global__ __launch_bounds__(256) void attn_kernel(
    const short* __restrict__ qh, const short* __restrict__ kh,
    const short* __restrict__ vt, const int* __restrict__ mask,
    float* __restrict__ out_h, float* __restrict__ out_s)
{
  const int bh = blockIdx.y;           // b*16 + h
  const int b  = bh >> 4;
  const int q0 = blockIdx.x * 64;

  const int tid  = threadIdx.x;
  const int w    = tid >> 6;
  const int lane = tid & 63;
  const int quad = lane >> 4;
  const int c    = lane & 15;

  __shared__ __align__(16) short Ksm[128 * 64];     // [key][d] swizzled
  __shared__ __align__(16) short Vsm[64 * 128];     // [d][key] swizzled
  __shared__ __align__(16) short Psm[4][16 * 136];  // per-wave P, padded
  __shared__ float maskadd[128];

  // Q fragments (A-operand): row m = c, k = ks*32 + quad*8 + j
  const short* qbase = qh + ((size_t)bh * SS + q0 + w * 16 + c) * HD;
  short8 qf[2];
  qf[0] = *(const short8*)&qbase[quad * 8];
  qf[1] = *(const short8*)&qbase[32 + quad * 8];

  // ---------------- pass 1: exp-sums ----------------
  float lsum[4] = {0.f, 0.f, 0.f, 0.f};
  for (int key0 = 0; key0 < SS; key0 += 128) {
    // stage K chunk: 1024 slots of 16B, 4 per thread
#pragma unroll
    for (int i = 0; i < 4; i++) {
      int slot = tid + i * 256;
      int row  = slot >> 3;
      int seg  = slot & 7;
      int gs   = seg ^ (row & 7);
      const short* src = kh + ((size_t)bh * SS + key0 + row) * HD + gs * 8;
      *(short8*)&Ksm[row * 64 + seg * 8] = *(const short8*)src;
    }
    if (tid < 128)
      maskadd[tid] = -10000.0f * (1.0f - (float)mask[b * SS + key0 + tid]);
    __syncthreads();

    floatx4 sacc[8];
#pragma unroll
    for (int s = 0; s < 8; s++) sacc[s] = (floatx4){0.f, 0.f, 0.f, 0.f};
#pragma unroll
    for (int ks = 0; ks < 2; ks++) {
#pragma unroll
      for (int sub = 0; sub < 8; sub++) {
        int kr = sub * 16 + c;
        short8 kf = *(short8*)&Ksm[kr * 64 + ((ks * 4 + quad) ^ (kr & 7)) * 8];
        sacc[sub] = __builtin_amdgcn_mfma_f32_16x16x32_bf16(qf[ks], kf, sacc[sub], 0, 0, 0);
      }
    }
#pragma unroll
    for (int sub = 0; sub < 8; sub++) {
      float ma = maskadd[sub * 16 + c];
#pragma unroll
      for (int r = 0; r < 4; r++) {
        float sc = fminf(sacc[sub][r] * 0.125f + ma, 30.0f);
        lsum[r] += __expf(sc);
      }
    }
    __syncthreads();
  }
  // reduce across the 16 lanes of each quad (cols); rows = quad*4+r
#pragma unroll
  for (int m = 1; m < 16; m <<= 1)
#pragma unroll
    for (int r = 0; r < 4; r++) lsum[r] += __shfl_xor(lsum[r], m);
  float rinv[4];
#pragma unroll
  for (int r = 0; r < 4; r++) rinv[r] = 1.0f / lsum[r];

  // ---------------- pass 2: write scores, accumulate O ----------------
  floatx4 oacc[4];
#pragma unroll
  for (int i = 0; i < 4; i++) oacc[i] = (floatx4){0.f, 0.f, 0.f, 0.f};

  for (int key0 = 0; key0 < SS; key0 += 128) {
#pragma unroll
    for (int i = 0; i < 4; i++) {
      int slot = tid + i * 256;
      // K chunk
      int row = slot >> 3;
      int seg = slot & 7;
      int gs  = seg ^ (row & 7);
      const short* src = kh + ((size_t)bh * SS + key0 + row) * HD + gs * 8;
      *(short8*)&Ksm[row * 64 + seg * 8] = *(const short8*)src;
      // V chunk from vt [B,H,D,S]: 64 rows(d) x 16 segs (128 keys)
      int vrow = slot >> 4;
      int vseg = slot & 15;
      int vgs  = vseg ^ (vrow & 7);
      const short* vsrc = vt + ((size_t)bh * HD + vrow) * SS + key0 + vgs * 8;
      *(short8*)&Vsm[vrow * 128 + vseg * 8] = *(const short8*)vsrc;
    }
    if (tid < 128)
      maskadd[tid] = -10000.0f * (1.0f - (float)mask[b * SS + key0 + tid]);
    __syncthreads();

    floatx4 sacc[8];
#pragma unroll
    for (int s = 0; s < 8; s++) sacc[s] = (floatx4){0.f, 0.f, 0.f, 0.f};
#pragma unroll
    for (int ks = 0; ks < 2; ks++) {
#pragma unroll
      for (int sub = 0; sub < 8; sub++) {
        int kr = sub * 16 + c;
        short8 kf = *(short8*)&Ksm[kr * 64 + ((ks * 4 + quad) ^ (kr & 7)) * 8];
        sacc[sub] = __builtin_amdgcn_mfma_f32_16x16x32_bf16(qf[ks], kf, sacc[sub], 0, 0, 0);
      }
    }

    // normalize, store scores (fp32), stage P (bf16) for PV
    float* srow_base = out_s + ((size_t)bh * SS + q0 + w * 16) * SS + key0;
#pragma unroll
    for (int sub = 0; sub < 8; sub++) {
      float ma = maskadd[sub * 16 + c];
#pragma unroll
      for (int r = 0; r < 4; r++) {
        float sc = fminf(sacc[sub][r] * 0.125f + ma, 30.0f);
        float p  = __expf(sc) * rinv[r];
        int qrow = quad * 4 + r;
        srow_base[(size_t)qrow * SS + sub * 16 + c] = p;
        Psm[w][qrow * 136 + sub * 16 + c] = f2bf(p);
      }
    }
    // PV: O[16 x 64] += P[16 x 128] · V[128 x 64] ; same-wave LDS dependency
#pragma unroll
    for (int kk = 0; kk < 4; kk++) {
      short8 pf = *(short8*)&Psm[w][c * 136 + kk * 32 + quad * 8];
#pragma unroll
      for (int ns = 0; ns < 4; ns++) {
        int vr = ns * 16 + c;
        short8 vf = *(short8*)&Vsm[vr * 128 + ((kk * 4 + quad) ^ (vr & 7)) * 8];
        oacc[ns] = __builtin_amdgcn_mfma_f32_16x16x32_bf16(pf, vf, oacc[ns], 0, 0, 0);
      }
    }
    __syncthreads();
  }

  // write h [B,S,HID]
  const int hh = bh & 15;
#pragma unroll
  for (int ns = 0; ns < 4; ns++) {
    int dd = ns * 16 + c;
#pragma unroll
    for (int r = 0; r < 4; r++) {
      int qrow = q0 + w * 16 + quad * 4 + r;
      out_h[((size_t)b * SS + qrow) * HIDD + hh * HD + dd] = oacc[ns][r];
    }
  }
}

// ---------------------------------------------------------------------------
extern "C" void kernel_launch(void* const* d_in, const int* in_sizes, int n_in,
                              void* d_out, int out_size, void* d_ws, size_t ws_size,
                              hipStream_t stream) {
  const float* q  = (const float*)d_in[0];
  const float* k  = (const float*)d_in[1];
  const float* v  = (const float*)d_in[2];
  const float* Wq = (const float*)d_in[3];
  const float* bq = (const float*)d_in[4];
  const float* Wk = (const float*)d_in[5];
  const float* bk = (const float*)d_in[6];
  const float* Wv = (const float*)d_in[7];
  const float* bv = (const float*)d_in[8];
  const int* mask = (const int*)d_in[9];

  float* out   = (float*)d_out;
  float* out_h = out;                       // 4*2048*1024 = 8388608 floats
  float* out_s = out + 8388608;             // 4*16*2048*2048 floats

  short* qh = (short*)d_ws;                 // bf16 [B,H,S,D]
  short* kh = qh + (size_t)8388608;         // bf16 [B,H,S,D]
  short* vt = kh + (size_t)8388608;         // bf16 [B,H,D,S]
  // ws needed: 3 * 16.78 MB = 50.3 MB

  dim3 pgrid(64, 8, 3);
  proj_kernel<<<pgrid, 256, 0, stream>>>(q, k, v, Wq, bq, Wk, bk, Wv, bv,
                                         qh, kh, vt);
  dim3 agrid(32, BH);
  attn_kernel<<<agrid, 256, 0, stream>>>(qh, kh, vt, mask, out_h, out_s);
}